// Round 8
// baseline (531.701 us; speedup 1.0000x reference)
//
#include <hip/hip_runtime.h>

#define T_LEN 512
#define D_DIM 32
#define N_DIM 64
#define B_ALL 128
#define R_TILE 8      // real batch rows per block (M=16 MFMA, rows permuted)
#define M_DIM 16      // MFMA M dimension
#define HSTR 72       // ushort row stride for sHh/sHl: 16B-aligned, bank-spread

typedef short s8v __attribute__((ext_vector_type(8)));   // 8 bf16 (4 VGPRs)
typedef float f4v __attribute__((ext_vector_type(4)));   // MFMA C/D
typedef float f2v __attribute__((ext_vector_type(2)));
typedef unsigned int uint;
typedef unsigned short u16;

__device__ __forceinline__ float rcp_f(float x) {
#if __has_builtin(__builtin_amdgcn_rcpf)
    return __builtin_amdgcn_rcpf(x);
#else
    return 1.0f / x;
#endif
}
__device__ __forceinline__ float tanh_f(float x) {
    float e = __expf(2.0f * x);
    return 1.0f - 2.0f * rcp_f(e + 1.0f);
}
__device__ __forceinline__ float sig_f(float x) {
    return rcp_f(1.0f + __expf(-x));
}
__device__ __forceinline__ uint f2bf(float f) {   // fp32 -> bf16 bits, RNE
    uint u = __float_as_uint(f);
    return (u + 0x7FFFu + ((u >> 16) & 1u)) >> 16;
}
__device__ __forceinline__ s8v pack4(uint a, uint b, uint c, uint d_) {
    union { uint u[4]; s8v v; } x;
    x.u[0] = a; x.u[1] = b; x.u[2] = c; x.u[3] = d_;
    return x.v;
}

// R7 structure (best: 490us): grid 512 (32 d x 16 row-octets) x 256 thr
// (4 waves) -> 2 independent blocks/CU; alpha reduction via 4 fan-vector
// MFMAs (no cross-lane ops); gate path exact R2.
// R8 delta (one unit, bitwise-identical): ANTI-PHASE START STAGGER.
// R7 counters showed MfmaUtil(43%) + VALUBusy(58%) = 101% of wall time --
// the two co-resident blocks are phase-LOCKED IN-PHASE: both burst MFMA
// together (VALU idle), then both run gate transcendentals together
// (matrix pipe idle); wall = 985 + 1334 = 2320cy/step, matching measured
// 2300. In-phase is stable under symmetric contention. A one-time ~640cy
// stagger (half the VALU phase) on one member of each co-resident pair
// flips the system toward anti-phase ping-pong: A's MFMA phase under B's
// VALU phase -> period ~ max-driven ~1334cy. Pairing is (i,i+256) if
// dispatch round-robins XCDs (bit 8) or (2i,2i+1) if consecutive (bit 0);
// the XOR parity (b ^ b>>8) & 1 staggers exactly one member under either.
// NOTE: C-fold of x*U+b into MFMA C-in regressed (R5/R6) - keep acc=0.
__global__ void __launch_bounds__(256, 2)
imv_lstm_scan(const float* __restrict__ x,
              const float* __restrict__ Uj, const float* __restrict__ Ui,
              const float* __restrict__ Uf, const float* __restrict__ Uo,
              const float* __restrict__ Wj, const float* __restrict__ Wi,
              const float* __restrict__ Wf, const float* __restrict__ Wo,
              const float* __restrict__ bj, const float* __restrict__ bi_,
              const float* __restrict__ bf_, const float* __restrict__ bo,
              const float* __restrict__ Fa, const float* __restrict__ Fab,
              const float* __restrict__ Fbw, const float* __restrict__ Fbb,
              const float* __restrict__ Pw, const float* __restrict__ Pb,
              float* __restrict__ wmu, float* __restrict__ wbeta)
{
    __shared__ float sXT[T_LEN][R_TILE];     // 16 KB, [t][r]
    __shared__ u16   sHh[2][M_DIM][HSTR];    // 4.5 KB, h hi bf16, [buf][Mrow][k]
    __shared__ u16   sHl[2][M_DIM][HSTR];    // 4.5 KB, h lo bf16
    __shared__ float sPS[R_TILE][4];         // epilogue mu partials
    __shared__ float sPV[R_TILE][4];         // epilogue beta partials

    const int tid  = threadIdx.x;
    const int lane = tid & 63;
    const int wg   = tid >> 6;               // 0..3 (n-group)
    const int quad = lane >> 4;              // 0..3
    const int col  = lane & 15;
    const int d    = blockIdx.x & 31;
    const int rt   = blockIdx.x >> 5;        // 0..15
    const int r0   = rt * R_TILE;
    const int n    = wg * 16 + col;          // this lane's n
    const int mrow = quad * 4;               // first M row of lane's 2 rows
    const int rrow = quad * 2;               // first real row of lane's 2

    // ---- stage x transposed: sXT[t][r] ----
    for (int i = tid; i < R_TILE * T_LEN; i += 256) {
        int t = i >> 3, r = i & 7;
        sXT[t][r] = x[((size_t)(r0 + r) * T_LEN + t) * D_DIM + d];
    }
    // ---- h0 = 0 (zero both buffers; unwritten M rows stay 0 forever) ----
    for (int i = tid; i < 2 * M_DIM * HSTR; i += 256) {
        ((u16*)sHh)[i] = 0; ((u16*)sHl)[i] = 0;
    }

    // ---- W fragments into registers: Bh/Bl[gate][k-chunk] ----
    s8v Bh[4][2], Bl[4][2];
    #pragma unroll
    for (int g = 0; g < 4; ++g) {
        const float* Wg = (g == 0 ? Wj : g == 1 ? Wi : g == 2 ? Wf : Wo)
                          + d * (N_DIM * N_DIM);
        #pragma unroll
        for (int c = 0; c < 2; ++c) {
            uint hp[4], lp[4];
            #pragma unroll
            for (int jp = 0; jp < 4; ++jp) {
                float w0 = Wg[(32 * c + quad * 8 + 2 * jp + 0) * N_DIM + n];
                float w1 = Wg[(32 * c + quad * 8 + 2 * jp + 1) * N_DIM + n];
                uint u0 = __float_as_uint(w0), u1 = __float_as_uint(w1);
                uint h0b = u0 & 0xFFFF0000u, h1b = u1 & 0xFFFF0000u;
                float l0 = w0 - __uint_as_float(h0b);
                float l1 = w1 - __uint_as_float(h1b);
                hp[jp] = (u0 >> 16) | h1b;
                lp[jp] = f2bf(l0) | (f2bf(l1) << 16);
            }
            Bh[g][c] = pack4(hp[0], hp[1], hp[2], hp[3]);
            Bl[g][c] = pack4(lp[0], lp[1], lp[2], lp[3]);
        }
    }

    // ---- fan-vector B fragment: B[k][col] = bf16(fan[k]), SAME for every
    //      col -> D[row][col] = sum_k h[row,k]*fan[k] lands in ALL lanes ----
    s8v Ff[2];
    #pragma unroll
    for (int c = 0; c < 2; ++c) {
        uint p[4];
        #pragma unroll
        for (int jp = 0; jp < 4; ++jp) {
            float f0 = Fa[d * N_DIM + 32 * c + quad * 8 + 2 * jp + 0];
            float f1 = Fa[d * N_DIM + 32 * c + quad * 8 + 2 * jp + 1];
            p[jp] = f2bf(f0) | (f2bf(f1) << 16);
        }
        Ff[c] = pack4(p[0], p[1], p[2], p[3]);
    }

    const int dn = d * N_DIM + n;
    const float u_j = Uj[dn], u_i = Ui[dn], u_f = Uf[dn], u_o = Uo[dn];
    const float cbj = bj[dn], cbi = bi_[dn], cbf = bf_[dn], cbo = bo[dn];
    const float fab = Fab[d];

    __syncthreads();

    // ---- anti-phase stagger: delay one member of each co-resident pair
    //      by ~640cy (half the VALU phase). Bitwise no-op. ----
    if (((blockIdx.x ^ (blockIdx.x >> 8)) & 1) != 0) {
#if __has_builtin(__builtin_amdgcn_s_sleep)
        __builtin_amdgcn_s_sleep(10);   // ~640 cycles
#else
        for (volatile int z = 0; z < 80; ++z) { }
#endif
    }

    float c_[2] = {0.f, 0.f};
    float h_[2] = {0.f, 0.f};
    float ga[2] = {0.f, 0.f};
    // as init cancels the spurious t=-1 alpha term exactly: at t=0 the
    // A-frags are exactly 0 -> af=0 -> al = exp(tanh(fab)).
    const float al_m1 = __expf(tanh_f(fab));
    float as[2] = {-al_m1, -al_m1};

    #pragma unroll 2
    for (int t = 0; t < T_LEN; ++t) {
        const int wb = t & 1;        // write buffer (h_t)
        const int rb = wb ^ 1;       // read buffer (h_{t-1})

        // ---- A fragments: direct b128 reads, zero unpack ----
        s8v Ah[2], Al[2];
        #pragma unroll
        for (int c = 0; c < 2; ++c) {
            Ah[c] = *(const s8v*)&sHh[rb][col][32 * c + quad * 8];
            Al[c] = *(const s8v*)&sHl[rb][col][32 * c + quad * 8];
        }

        // ---- alpha logit for step t-1 via MFMA (2 independent 2-chains) ----
        f4v af0 = {0.f, 0.f, 0.f, 0.f};
        f4v af1 = {0.f, 0.f, 0.f, 0.f};
        af0 = __builtin_amdgcn_mfma_f32_16x16x32_bf16(Ah[0], Ff[0], af0, 0, 0, 0);
        af0 = __builtin_amdgcn_mfma_f32_16x16x32_bf16(Al[0], Ff[0], af0, 0, 0, 0);
        af1 = __builtin_amdgcn_mfma_f32_16x16x32_bf16(Ah[1], Ff[1], af1, 0, 0, 0);
        af1 = __builtin_amdgcn_mfma_f32_16x16x32_bf16(Al[1], Ff[1], af1, 0, 0, 0);

        // ---- 24 gate MFMAs: exact R2 (single acc chain, zero C-in) ----
        f4v acc[4];
        #pragma unroll
        for (int g = 0; g < 4; ++g) {
            f4v a = {0.f, 0.f, 0.f, 0.f};
            #pragma unroll
            for (int c = 0; c < 2; ++c) {
                a = __builtin_amdgcn_mfma_f32_16x16x32_bf16(Ah[c], Bh[g][c], a, 0, 0, 0);
                a = __builtin_amdgcn_mfma_f32_16x16x32_bf16(Al[c], Bh[g][c], a, 0, 0, 0);
                a = __builtin_amdgcn_mfma_f32_16x16x32_bf16(Ah[c], Bl[g][c], a, 0, 0, 0);
            }
            acc[g] = a;
        }

        // ---- alpha(t-1): independent of the gate chain, uses OLD h_ ----
        #pragma unroll
        for (int r = 0; r < 2; ++r) {
            float tot = af0[r] + af1[r] + fab;
            float al = __expf(tanh_f(tot));
            as[r] += al;
            ga[r] = fmaf(al, h_[r], ga[r]);
        }

        // ---- stage 3: C regs 0,1 = real rows rrow, rrow+1 at n ----
        f2v xr = *(const f2v*)&sXT[t][rrow];
        #pragma unroll
        for (int r = 0; r < 2; ++r) {
            float xv = xr[r];
            float jp = acc[0][r] + fmaf(xv, u_j, cbj);
            float ip = acc[1][r] + fmaf(xv, u_i, cbi);
            float fp = acc[2][r] + fmaf(xv, u_f, cbf);
            float op = acc[3][r] + fmaf(xv, u_o, cbo);
            c_[r] = fmaf(c_[r], sig_f(fp), sig_f(ip) * tanh_f(jp));
            h_[r] = sig_f(op) * tanh_f(c_[r]);
        }

        // ---- write h_t (hi/lo planes, M rows mrow..mrow+1) ----
        #pragma unroll
        for (int r = 0; r < 2; ++r) {
            float hv = h_[r];
            uint u = __float_as_uint(hv);
            uint hb = u & 0xFFFF0000u;
            float lo = hv - __uint_as_float(hb);
            sHh[wb][mrow + r][n] = (u16)(u >> 16);
            sHl[wb][mrow + r][n] = (u16)f2bf(lo);
        }

        __syncthreads();   // the ONLY barrier: h_t planes visible
    }

    // ---- drain alpha(T-1): h_{T-1} is in buffer (T-1)&1 = 1 ----
    {
        s8v Ah[2], Al[2];
        #pragma unroll
        for (int c = 0; c < 2; ++c) {
            Ah[c] = *(const s8v*)&sHh[1][col][32 * c + quad * 8];
            Al[c] = *(const s8v*)&sHl[1][col][32 * c + quad * 8];
        }
        f4v af0 = {0.f, 0.f, 0.f, 0.f};
        f4v af1 = {0.f, 0.f, 0.f, 0.f};
        af0 = __builtin_amdgcn_mfma_f32_16x16x32_bf16(Ah[0], Ff[0], af0, 0, 0, 0);
        af0 = __builtin_amdgcn_mfma_f32_16x16x32_bf16(Al[0], Ff[0], af0, 0, 0, 0);
        af1 = __builtin_amdgcn_mfma_f32_16x16x32_bf16(Ah[1], Ff[1], af1, 0, 0, 0);
        af1 = __builtin_amdgcn_mfma_f32_16x16x32_bf16(Al[1], Ff[1], af1, 0, 0, 0);
        #pragma unroll
        for (int r = 0; r < 2; ++r) {
            float tot = af0[r] + af1[r] + fab;
            float al = __expf(tanh_f(tot));
            as[r] += al;
            ga[r] = fmaf(al, h_[r], ga[r]);
        }
    }

    // ---- epilogue: mu, beta per (row, d) ----
    const float pwa = Pw[n],  pwb = Pw[64 + n];
    const float fwa = Fbw[n], fwb = Fbw[64 + n];
    float pm[2], pv[2];
    #pragma unroll
    for (int r = 0; r < 2; ++r) {
        float gn = ga[r] * rcp_f(as[r]);
        pm[r] = fmaf(gn, pwa, h_[r] * pwb);
        pv[r] = fmaf(gn, fwa, h_[r] * fwb);
        pm[r] += __shfl_xor(pm[r], 1); pm[r] += __shfl_xor(pm[r], 2);
        pm[r] += __shfl_xor(pm[r], 4); pm[r] += __shfl_xor(pm[r], 8);
        pv[r] += __shfl_xor(pv[r], 1); pv[r] += __shfl_xor(pv[r], 2);
        pv[r] += __shfl_xor(pv[r], 4); pv[r] += __shfl_xor(pv[r], 8);
    }
    if (col == 0) {
        #pragma unroll
        for (int r = 0; r < 2; ++r) {
            sPS[rrow + r][wg] = pm[r];
            sPV[rrow + r][wg] = pv[r];
        }
    }
    __syncthreads();
    if (tid < R_TILE) {
        int r = tid;
        f4v a  = *(const f4v*)&sPS[r][0];
        f4v b2 = *(const f4v*)&sPV[r][0];
        float mu = a[0] + a[1] + a[2] + a[3] + Pb[0];
        float bt = __expf(tanh_f(b2[0] + b2[1] + b2[2] + b2[3] + Fbb[0]));
        wmu  [(r0 + r) * D_DIM + d] = mu;
        wbeta[(r0 + r) * D_DIM + d] = bt;
    }
}

// beta softmax over d + weighted sum -> out[b]
__global__ void imv_finalize(const float* __restrict__ wmu,
                             const float* __restrict__ wbeta,
                             float* __restrict__ out)
{
    int b = blockIdx.x * 64 + threadIdx.x;
    if (b >= B_ALL) return;
    float s1 = 0.f, s2 = 0.f;
    for (int d = 0; d < D_DIM; ++d) {
        float be = wbeta[b * D_DIM + d];
        s1 = fmaf(be, wmu[b * D_DIM + d], s1);
        s2 += be;
    }
    out[b] = s1 / s2;
}

extern "C" void kernel_launch(void* const* d_in, const int* in_sizes, int n_in,
                              void* d_out, int out_size, void* d_ws, size_t ws_size,
                              hipStream_t stream)
{
    const float* x   = (const float*)d_in[0];
    const float* U_j = (const float*)d_in[1];
    const float* U_i = (const float*)d_in[2];
    const float* U_f = (const float*)d_in[3];
    const float* U_o = (const float*)d_in[4];
    const float* W_j = (const float*)d_in[5];
    const float* W_i = (const float*)d_in[6];
    const float* W_f = (const float*)d_in[7];
    const float* W_o = (const float*)d_in[8];
    const float* b_j = (const float*)d_in[9];
    const float* b_i = (const float*)d_in[10];
    const float* b_f = (const float*)d_in[11];
    const float* b_o = (const float*)d_in[12];
    const float* Fan  = (const float*)d_in[13];
    const float* Fanb = (const float*)d_in[14];
    const float* Fbw  = (const float*)d_in[15];
    const float* Fbb  = (const float*)d_in[16];
    const float* Phw  = (const float*)d_in[17];
    const float* Phb  = (const float*)d_in[18];

    float* wmu   = (float*)d_ws;
    float* wbeta = wmu + B_ALL * D_DIM;

    imv_lstm_scan<<<dim3(512), dim3(256), 0, stream>>>(
        x, U_j, U_i, U_f, U_o, W_j, W_i, W_f, W_o,
        b_j, b_i, b_f, b_o, Fan, Fanb, Fbw, Fbb, Phw, Phb,
        wmu, wbeta);

    imv_finalize<<<dim3(2), dim3(64), 0, stream>>>(wmu, wbeta, (float*)d_out);
}